// Round 8
// baseline (3503.370 us; speedup 1.0000x reference)
//
#include <hip/hip_runtime.h>
#include <hip/hip_bf16.h>
#include <stdint.h>

#define B_ 256
#define S_ 64
#define D_ 256
#define H_ 1024
#define O_ 512
#define G_ 3072          // 3*H
#define BH_ (B_ * H_)    // 262144
#define RING_ 32

typedef unsigned short u16;
typedef __attribute__((ext_vector_type(8))) short bf16x8;
typedef __attribute__((ext_vector_type(4))) float f32x4;

#define MFMA16(a, b, c) __builtin_amdgcn_mfma_f32_16x16x32_bf16((a), (b), (c), 0, 0, 0)

__device__ __forceinline__ u16 f2b(float f) {
    union { float f; uint32_t u; } v; v.f = f;
    uint32_t u = v.u;
    return (u16)((u + 0x7fffu + ((u >> 16) & 1u)) >> 16);   // RNE
}

// system-coherent 8B load/store: pure vmcnt, bypasses non-coherent caches
__device__ __forceinline__ unsigned long long gld_sys(const u16* p) {
    unsigned long long v;
    asm volatile("global_load_dwordx2 %0, %1, off sc0 sc1"
                 : "=v"(v) : "v"(p) : "memory");
    return v;
}
__device__ __forceinline__ void gst_sys(u16* p, unsigned long long v) {
    asm volatile("global_store_dwordx2 %0, %1, off sc0 sc1"
                 :: "v"(p), "v"(v) : "memory");
}
__device__ __forceinline__ void waitflag(int* f, int n) {
    while (__hip_atomic_load(f, __ATOMIC_RELAXED, __HIP_MEMORY_SCOPE_SYSTEM) < n)
        __builtin_amdgcn_s_sleep(8);
    asm volatile("" ::: "memory");
}
__device__ __forceinline__ void postflag(int* f) {
    __hip_atomic_fetch_add(f, 1, __ATOMIC_RELAXED, __HIP_MEMORY_SCOPE_SYSTEM);
}

// ---------------- prep kernels ----------------

__global__ void k_conv(const float* __restrict__ s, u16* __restrict__ d, int n4) {
    int i = blockIdx.x * blockDim.x + threadIdx.x;
    int st = gridDim.x * blockDim.x;
    for (; i < n4; i += st) {
        float4 v = ((const float4*)s)[i];
        ushort4 o;
        o.x = f2b(v.x); o.y = f2b(v.y); o.z = f2b(v.z); o.w = f2b(v.w);
        ((ushort4*)d)[i] = o;
    }
}

// lin_w [S][H][O] f32 -> [S][O][H] bf16
__global__ __launch_bounds__(256) void k_twl(const float* __restrict__ w, u16* __restrict__ o) {
    __shared__ float tile[32][33];
    int bid = blockIdx.x;
    int t = bid >> 9;
    int rem = bid & 511;
    int j0 = (rem >> 4) << 5;
    int o0 = (rem & 15) << 5;
    int tx = threadIdx.x & 31, ty = threadIdx.x >> 5;
    const float* base = w + (size_t)t * (H_ * O_);
#pragma unroll
    for (int i = 0; i < 4; ++i) {
        int r = ty + (i << 3);
        tile[r][tx] = base[(size_t)(j0 + r) * O_ + o0 + tx];
    }
    __syncthreads();
    u16* ob = o + (size_t)t * (O_ * H_);
#pragma unroll
    for (int i = 0; i < 4; ++i) {
        int r = ty + (i << 3);
        ob[(size_t)(o0 + r) * H_ + j0 + tx] = f2b(tile[tx][r]);
    }
}

// ---------------- persistent dataflow GRU + linear head ----------------
// Weights: global -> VGPR MFMA fragments directly (no LDS), 4-body modulo-
// scheduled prefetch with exact per-wave vmcnt ledger. A: sys-load -> reg ->
// LDS double buffer (dedup point across the 8 waves).

struct GruArgs {
    const u16* Xb;
    const u16 *Wi0, *Wh0, *Wi1, *Wh1, *Wi2, *Wh2;
    const float *bi0, *bh0, *bi1, *bh1, *bi2, *bh2;
    u16 *h0, *h1, *h2a;      // h0,h1: 32-slot rings; h2a: 65 slots (slot t+1 = time t)
    const u16* WLt;          // [S][O][H] bf16
    const float* lb;         // [S][O]
    float* out;              // [B][S][O] then h0,h1,h2 finals
    int* ready;              // [3 cells][64 t]   -> counts to 64
    int* consumed;           // [2 cells][64 t]   -> counts to 128
};

#define VMW(n)  asm volatile("s_waitcnt vmcnt(" #n ")" ::: "memory")
#define LGK0    asm volatile("s_waitcnt lgkmcnt(0)" ::: "memory")
#define SBAR    __builtin_amdgcn_s_barrier()
#define SCHB    __builtin_amdgcn_sched_barrier(0)

__global__ __launch_bounds__(512, 1) void k_gru(GruArgs p) {
    __shared__ u16 Ab[2][32 * 64];       // 8 KiB A double-buffer
    __shared__ u16 hrep[32 * 128];       // 8 KiB bf16 repack staging

    const int w = blockIdx.x;
    const int xcd = w & 7;               // weight j-slice owner (targets XCD via %8)
    const int slot = w >> 3;             // 0..31
    const int role = slot >> 3;          // 0,1,2 = GRU cells; 3 = linear head
    const int sub = slot & 7;            // batch tile
    const int b0 = sub * 32;

    const int tid = threadIdx.x;
    const int wid = tid >> 6, lane = tid & 63;
    const int fr = lane & 15, kc = lane >> 4;

    // A staging constants (A-tile: 32 rows x 64 k, 8B per thread)
    const int arow = tid >> 4;
    const int acol = (tid & 15) << 2;                                        // u16 offset
    const int adst = arow * 64 + ((((tid & 15) >> 1) ^ (arow & 7)) << 3) + ((tid & 1) << 2);

    const int sw0 = ((kc ^ (fr & 7)) << 3);
    const int sw1 = (((4 + kc) ^ (fr & 7)) << 3);
    const int koff = kc << 3;            // lane k offset within a 64-chunk

    int* ready = p.ready;
    int* consumed = p.consumed;

    if (role < 3) {
        // ================= GRU cell =================
        const u16 *Wi, *Wh; const float *bi, *bh; int K0;
        if (role == 0)      { Wi = p.Wi0; Wh = p.Wh0; bi = p.bi0; bh = p.bh0; K0 = D_; }
        else if (role == 1) { Wi = p.Wi1; Wh = p.Wh1; bi = p.bi1; bh = p.bh1; K0 = H_; }
        else                { Wi = p.Wi2; Wh = p.Wh2; bi = p.bi2; bh = p.bh2; K0 = H_; }
        const int nXc = K0 >> 6;
        const int nC = nXc + 16;         // 20 or 32 (divisible by 4)
        const int j0 = xcd * 128;        // weight slice fixed per XCD
        const int jrow = (wid << 4) + fr;
        const int jme = j0 + jrow;
        const float b_r = bi[jme] + bh[jme];
        const float b_z = bi[H_ + jme] + bh[H_ + jme];
        const float b_i = bi[2 * H_ + jme];
        const float b_h = bh[2 * H_ + jme];

        const size_t rowX = (size_t)jme * K0;
        const size_t rowH = (size_t)jme * H_;
        const size_t gsX = (size_t)H_ * K0;
        const size_t gsH = (size_t)H_ * H_;

        const u16 *A0 = nullptr, *Ah = nullptr; int ld0 = H_;
        u16* hout = nullptr;

        f32x4 hcar[2] = {};              // fp32 recurrent carry in registers

        auto LA = [&](int c) -> unsigned long long {
            const u16* s = (c < nXc) ? (A0 + (size_t)arow * ld0 + (c << 6) + acol)
                                     : (Ah + (size_t)arow * H_ + ((c - nXc) << 6) + acol);
            return gld_sys(s);
        };

#define WISS(cc_, W0,W1,W2,W3,W4,W5) do { \
    int c_ = (cc_); const u16* bx_; size_t gs_; \
    if (c_ < nXc) { bx_ = Wi + rowX + ((size_t)c_ << 6) + koff; gs_ = gsX; } \
    else          { bx_ = Wh + rowH + ((size_t)(c_ - nXc) << 6) + koff; gs_ = gsH; } \
    asm volatile("global_load_dwordx4 %0, %1, off" : "=v"(W0) : "v"(bx_)); \
    asm volatile("global_load_dwordx4 %0, %1, off" : "=v"(W1) : "v"(bx_ + 32)); \
    asm volatile("global_load_dwordx4 %0, %1, off" : "=v"(W2) : "v"(bx_ + gs_)); \
    asm volatile("global_load_dwordx4 %0, %1, off" : "=v"(W3) : "v"(bx_ + gs_ + 32)); \
    asm volatile("global_load_dwordx4 %0, %1, off" : "=v"(W4) : "v"(bx_ + 2 * gs_)); \
    asm volatile("global_load_dwordx4 %0, %1, off" : "=v"(W5) : "v"(bx_ + 2 * gs_ + 32)); \
} while (0)

#define CSTEP(ss_, RING, W0,W1,W2,W3,W4,W5, NIMM) do { \
    asm volatile("s_waitcnt vmcnt(" #NIMM ")" ::: "memory"); \
    SBAR; SCHB; \
    const int s_ = (ss_); const int cur_ = s_ & 1; \
    if (s_ + 1 < nC) *(unsigned long long*)&Ab[cur_ ^ 1][adst] = RING; \
    bf16x8 a00 = *(const bf16x8*)&Ab[cur_][fr * 64 + sw0]; \
    bf16x8 a01 = *(const bf16x8*)&Ab[cur_][fr * 64 + sw1]; \
    bf16x8 a10 = *(const bf16x8*)&Ab[cur_][(16 + fr) * 64 + sw0]; \
    bf16x8 a11 = *(const bf16x8*)&Ab[cur_][(16 + fr) * 64 + sw1]; \
    LGK0; SCHB; \
    __builtin_amdgcn_s_setprio(1); \
    { bf16x8 r0_ = *(const bf16x8*)&W0, r1_ = *(const bf16x8*)&W1; \
      bf16x8 z0_ = *(const bf16x8*)&W2, z1_ = *(const bf16x8*)&W3; \
      bf16x8 q0_ = *(const bf16x8*)&W4, q1_ = *(const bf16x8*)&W5; \
      accR[0] = MFMA16(a00, r0_, accR[0]); accR[0] = MFMA16(a01, r1_, accR[0]); \
      accR[1] = MFMA16(a10, r0_, accR[1]); accR[1] = MFMA16(a11, r1_, accR[1]); \
      accZ[0] = MFMA16(a00, z0_, accZ[0]); accZ[0] = MFMA16(a01, z1_, accZ[0]); \
      accZ[1] = MFMA16(a10, z0_, accZ[1]); accZ[1] = MFMA16(a11, z1_, accZ[1]); \
      if (s_ < nXc) { \
        accI[0] = MFMA16(a00, q0_, accI[0]); accI[0] = MFMA16(a01, q1_, accI[0]); \
        accI[1] = MFMA16(a10, q0_, accI[1]); accI[1] = MFMA16(a11, q1_, accI[1]); \
      } else { \
        accN[0] = MFMA16(a00, q0_, accN[0]); accN[0] = MFMA16(a01, q1_, accN[0]); \
        accN[1] = MFMA16(a10, q0_, accN[1]); accN[1] = MFMA16(a11, q1_, accN[1]); \
      } } \
    __builtin_amdgcn_s_setprio(0); SCHB; \
    if (s_ + 5 < nC) RING = LA(s_ + 5); \
    if (s_ + 4 < nC) WISS(s_ + 4, W0, W1, W2, W3, W4, W5); \
} while (0)

        uint4 w00, w01, w02, w03, w04, w05;
        uint4 w10, w11, w12, w13, w14, w15;
        uint4 w20, w21, w22, w23, w24, w25;
        uint4 w30, w31, w32, w33, w34, w35;
        unsigned long long rA0, rA1, rA2, rA3;

        for (int t = 0; t < S_; ++t) {
            if (role == 0) {
                if (t) waitflag(&ready[0 * 64 + t - 1], 64);
                A0 = p.Xb + (size_t)b0 * (S_ * D_) + t * D_; ld0 = S_ * D_;
                Ah = p.h0 + (size_t)((t + RING_ - 1) & (RING_ - 1)) * BH_ + (size_t)b0 * H_;
                hout = p.h0 + (size_t)(t & (RING_ - 1)) * BH_;
            } else if (role == 1) {
                waitflag(&ready[0 * 64 + t], 64);
                if (t) waitflag(&ready[1 * 64 + t - 1], 64);
                A0 = p.h0 + (size_t)(t & (RING_ - 1)) * BH_ + (size_t)b0 * H_; ld0 = H_;
                Ah = p.h1 + (size_t)((t + RING_ - 1) & (RING_ - 1)) * BH_ + (size_t)b0 * H_;
                hout = p.h1 + (size_t)(t & (RING_ - 1)) * BH_;
            } else {
                waitflag(&ready[1 * 64 + t], 64);
                if (t) waitflag(&ready[2 * 64 + t - 1], 64);
                A0 = p.h1 + (size_t)(t & (RING_ - 1)) * BH_ + (size_t)b0 * H_; ld0 = H_;
                Ah = p.h2a + (size_t)t * BH_ + (size_t)b0 * H_;
                hout = p.h2a + (size_t)(t + 1) * BH_;
            }

            f32x4 accR[2] = {}, accZ[2] = {}, accI[2] = {}, accN[2] = {};

            // prologue: LA(0); then per phase u: LA(u+1), W(u)  -> 29 vm ops
            unsigned long long t0 = LA(0);
            rA0 = LA(1); WISS(0, w00, w01, w02, w03, w04, w05);
            rA1 = LA(2); WISS(1, w10, w11, w12, w13, w14, w15);
            rA2 = LA(3); WISS(2, w20, w21, w22, w23, w24, w25);
            rA3 = LA(4); WISS(3, w30, w31, w32, w33, w34, w35);
            VMW(28);                       // LA(0) complete
            *(unsigned long long*)&Ab[0][adst] = t0;

            int s4 = 0;
            for (; s4 + 7 < nC; s4 += 4) {
                CSTEP(s4 + 0, rA0, w00, w01, w02, w03, w04, w05, 21);
                CSTEP(s4 + 1, rA1, w10, w11, w12, w13, w14, w15, 21);
                CSTEP(s4 + 2, rA2, w20, w21, w22, w23, w24, w25, 21);
                CSTEP(s4 + 3, rA3, w30, w31, w32, w33, w34, w35, 21);
            }
            CSTEP(nC - 4, rA0, w00, w01, w02, w03, w04, w05, 20);
            CSTEP(nC - 3, rA1, w10, w11, w12, w13, w14, w15, 13);
            CSTEP(nC - 2, rA2, w20, w21, w22, w23, w24, w25, 6);
            CSTEP(nC - 1, rA3, w30, w31, w32, w33, w34, w35, 0);

            // ring backpressure before overwriting slot t & 31
            if (role <= 1 && t >= RING_) waitflag(&consumed[role * 64 + (t - RING_)], 128);

            // gates + state update; fp32 carry in regs, bf16 repack via LDS
#pragma unroll
            for (int m = 0; m < 2; ++m)
#pragma unroll
                for (int i = 0; i < 4; ++i) {
                    int row = m * 16 + kc * 4 + i;
                    float rv = 1.f / (1.f + __expf(-(accR[m][i] + b_r)));
                    float zv = 1.f / (1.f + __expf(-(accZ[m][i] + b_z)));
                    float nv = tanhf(accI[m][i] + b_i + rv * (accN[m][i] + b_h));
                    float hn = (1.f - zv) * nv + zv * hcar[m][i];
                    hcar[m][i] = hn;
                    hrep[row * 128 + (wid << 4) + fr] = f2b(hn);
                }
            __syncthreads();
            {
                int rr = tid >> 4, jo = (tid & 15) << 3;
                unsigned long long v0 = *(const unsigned long long*)&hrep[rr * 128 + jo];
                unsigned long long v1 = *(const unsigned long long*)&hrep[rr * 128 + jo + 4];
                u16* dst = hout + (size_t)(b0 + rr) * H_ + j0 + jo;
                gst_sys(dst, v0);
                gst_sys(dst + 4, v1);
            }
            if (t == S_ - 1) {
                float* ob = p.out + (size_t)B_ * S_ * O_ + (size_t)role * BH_;
#pragma unroll
                for (int m = 0; m < 2; ++m)
#pragma unroll
                    for (int i = 0; i < 4; ++i) {
                        int row = m * 16 + kc * 4 + i;
                        ob[(size_t)(b0 + row) * H_ + jme] = hcar[m][i];
                    }
            }
            asm volatile("s_waitcnt vmcnt(0)" ::: "memory");
            __syncthreads();
            if (tid == 0) {
                postflag(&ready[role * 64 + t]);
                if (role == 0) { if (t) postflag(&consumed[0 * 64 + t - 1]); }
                else if (role == 1) {
                    postflag(&consumed[0 * 64 + t]);
                    if (t) postflag(&consumed[1 * 64 + t - 1]);
                } else {
                    postflag(&consumed[1 * 64 + t]);
                }
            }
            __syncthreads();
            asm volatile("s_waitcnt vmcnt(0) lgkmcnt(0)" ::: "memory");  // ledger reset
        }
#undef CSTEP
#undef WISS
    } else {
        // ================= linear head =================
        const int o0 = xcd << 6;         // o-slice fixed per XCD
        const int nC = 16;
        const int mg = wid >> 2, og = wid & 3;
        const size_t rowO = (size_t)(o0 + og * 16 + fr) * H_;
        const u16 *A0 = nullptr, *Wl = nullptr;

        auto LAl = [&](int c) -> unsigned long long {
            return gld_sys(A0 + (size_t)arow * H_ + (c << 6) + acol);
        };

#define WLISS(cc_, W0, W1) do { int c_ = (cc_); \
    const u16* bx_ = Wl + rowO + ((size_t)c_ << 6) + koff; \
    asm volatile("global_load_dwordx4 %0, %1, off" : "=v"(W0) : "v"(bx_)); \
    asm volatile("global_load_dwordx4 %0, %1, off" : "=v"(W1) : "v"(bx_ + 32)); \
} while (0)

#define HSTEP(ss_, RING, W0, W1, NIMM) do { \
    asm volatile("s_waitcnt vmcnt(" #NIMM ")" ::: "memory"); \
    SBAR; SCHB; \
    const int s_ = (ss_); const int cur_ = s_ & 1; \
    if (s_ + 1 < nC) *(unsigned long long*)&Ab[cur_ ^ 1][adst] = RING; \
    bf16x8 a0 = *(const bf16x8*)&Ab[cur_][(mg * 16 + fr) * 64 + sw0]; \
    bf16x8 a1 = *(const bf16x8*)&Ab[cur_][(mg * 16 + fr) * 64 + sw1]; \
    LGK0; SCHB; \
    __builtin_amdgcn_s_setprio(1); \
    { bf16x8 w0_ = *(const bf16x8*)&W0, w1_ = *(const bf16x8*)&W1; \
      acc = MFMA16(a0, w0_, acc); \
      acc = MFMA16(a1, w1_, acc); } \
    __builtin_amdgcn_s_setprio(0); SCHB; \
    if (s_ + 5 < nC) RING = LAl(s_ + 5); \
    if (s_ + 4 < nC) WLISS(s_ + 4, W0, W1); \
} while (0)

        uint4 h00, h01, h10, h11, h20, h21, h30, h31;
        unsigned long long rA0, rA1, rA2, rA3;

        for (int t = 0; t < S_; ++t) {
            waitflag(&ready[2 * 64 + t], 64);
            A0 = p.h2a + (size_t)(t + 1) * BH_ + (size_t)b0 * H_;
            Wl = p.WLt + (size_t)t * (O_ * H_);

            f32x4 acc = {0.f, 0.f, 0.f, 0.f};
            unsigned long long t0 = LAl(0);
            rA0 = LAl(1); WLISS(0, h00, h01);
            rA1 = LAl(2); WLISS(1, h10, h11);
            rA2 = LAl(3); WLISS(2, h20, h21);
            rA3 = LAl(4); WLISS(3, h30, h31);
            VMW(12);                       // LAl(0) complete
            *(unsigned long long*)&Ab[0][adst] = t0;

            int s4 = 0;
            for (; s4 + 7 < nC; s4 += 4) {
                HSTEP(s4 + 0, rA0, h00, h01, 9);
                HSTEP(s4 + 1, rA1, h10, h11, 9);
                HSTEP(s4 + 2, rA2, h20, h21, 9);
                HSTEP(s4 + 3, rA3, h30, h31, 9);
            }
            HSTEP(nC - 4, rA0, h00, h01, 8);
            HSTEP(nC - 3, rA1, h10, h11, 5);
            HSTEP(nC - 2, rA2, h20, h21, 2);
            HSTEP(nC - 1, rA3, h30, h31, 0);

            float bb = p.lb[t * O_ + o0 + og * 16 + fr];
#pragma unroll
            for (int i = 0; i < 4; ++i) {
                int row = mg * 16 + kc * 4 + i;
                p.out[((size_t)(b0 + row) * S_ + t) * O_ + o0 + og * 16 + fr] = acc[i] + bb;
            }
            asm volatile("s_waitcnt vmcnt(0) lgkmcnt(0)" ::: "memory");  // ledger reset
        }
#undef HSTEP
#undef WLISS
    }
}

// ---------------- launch ----------------

extern "C" void kernel_launch(void* const* d_in, const int* in_sizes, int n_in,
                              void* d_out, int out_size, void* d_ws, size_t ws_size,
                              hipStream_t stream) {
    (void)in_sizes; (void)n_in; (void)out_size; (void)ws_size;
    const float* x   = (const float*)d_in[0];
    const float* wi0 = (const float*)d_in[1];
    const float* wh0 = (const float*)d_in[2];
    const float* bi0 = (const float*)d_in[3];
    const float* bh0 = (const float*)d_in[4];
    const float* wi1 = (const float*)d_in[5];
    const float* wh1 = (const float*)d_in[6];
    const float* bi1 = (const float*)d_in[7];
    const float* bh1 = (const float*)d_in[8];
    const float* wi2 = (const float*)d_in[9];
    const float* wh2 = (const float*)d_in[10];
    const float* bi2 = (const float*)d_in[11];
    const float* bh2 = (const float*)d_in[12];
    const float* lw  = (const float*)d_in[13];
    const float* lb  = (const float*)d_in[14];

    char* base = (char*)d_ws;
    size_t off = 0;
    auto alloc = [&](size_t bytes) {
        char* p = base + off;
        off = (off + bytes + 255) & ~(size_t)255;
        return p;
    };
    u16* Xb  = (u16*)alloc((size_t)B_ * S_ * D_ * 2);
    u16* Wi0 = (u16*)alloc((size_t)G_ * D_ * 2);
    u16* Wh0 = (u16*)alloc((size_t)G_ * H_ * 2);
    u16* Wi1 = (u16*)alloc((size_t)G_ * H_ * 2);
    u16* Wh1 = (u16*)alloc((size_t)G_ * H_ * 2);
    u16* Wi2 = (u16*)alloc((size_t)G_ * H_ * 2);
    u16* Wh2 = (u16*)alloc((size_t)G_ * H_ * 2);
    u16* h0  = (u16*)alloc((size_t)RING_ * BH_ * 2);
    u16* h1  = (u16*)alloc((size_t)RING_ * BH_ * 2);
    u16* h2a = (u16*)alloc((size_t)(S_ + 1) * BH_ * 2);
    u16* WLt = (u16*)alloc((size_t)S_ * O_ * H_ * 2);
    int* flags = (int*)alloc((size_t)(3 * 64 + 2 * 64) * 4);
    int* ready = flags;
    int* consumed = flags + 3 * 64;

    k_conv<<<1024, 256, 0, stream>>>(x,   Xb,  (B_ * S_ * D_) / 4);
    k_conv<<<1024, 256, 0, stream>>>(wi0, Wi0, (G_ * D_) / 4);
    k_conv<<<1024, 256, 0, stream>>>(wh0, Wh0, (G_ * H_) / 4);
    k_conv<<<1024, 256, 0, stream>>>(wi1, Wi1, (G_ * H_) / 4);
    k_conv<<<1024, 256, 0, stream>>>(wh1, Wh1, (G_ * H_) / 4);
    k_conv<<<1024, 256, 0, stream>>>(wi2, Wi2, (G_ * H_) / 4);
    k_conv<<<1024, 256, 0, stream>>>(wh2, Wh2, (G_ * H_) / 4);
    k_twl<<<S_ * 512, 256, 0, stream>>>(lw, WLt);
    hipMemsetAsync(h0 + (size_t)(RING_ - 1) * BH_, 0, (size_t)BH_ * 2, stream);  // h0[-1]=0
    hipMemsetAsync(h1 + (size_t)(RING_ - 1) * BH_, 0, (size_t)BH_ * 2, stream);  // h1[-1]=0
    hipMemsetAsync(h2a, 0, (size_t)BH_ * 2, stream);                             // h2[-1]=0
    hipMemsetAsync(flags, 0, (size_t)(3 * 64 + 2 * 64) * 4, stream);

    GruArgs ga;
    ga.Xb = Xb;
    ga.Wi0 = Wi0; ga.Wh0 = Wh0; ga.Wi1 = Wi1; ga.Wh1 = Wh1; ga.Wi2 = Wi2; ga.Wh2 = Wh2;
    ga.bi0 = bi0; ga.bh0 = bh0; ga.bi1 = bi1; ga.bh1 = bh1; ga.bi2 = bi2; ga.bh2 = bh2;
    ga.h0 = h0; ga.h1 = h1; ga.h2a = h2a;
    ga.WLt = WLt; ga.lb = lb; ga.out = (float*)d_out;
    ga.ready = ready; ga.consumed = consumed;

    void* args[] = {&ga};
    hipLaunchCooperativeKernel((void*)k_gru, dim3(256), dim3(512), args, 0, stream);
}

// Round 9
// 2756.847 us; speedup vs baseline: 1.2708x; 1.2708x over previous
//
#include <hip/hip_runtime.h>
#include <hip/hip_bf16.h>
#include <stdint.h>

#define B_ 256
#define S_ 64
#define D_ 256
#define H_ 1024
#define O_ 512
#define G_ 3072          // 3*H
#define BH_ (B_ * H_)    // 262144
#define RING_ 32

typedef unsigned short u16;
typedef __attribute__((ext_vector_type(8))) short bf16x8;
typedef __attribute__((ext_vector_type(4))) float f32x4;

#define MFMA16(a, b, c) __builtin_amdgcn_mfma_f32_16x16x32_bf16((a), (b), (c), 0, 0, 0)

__device__ __forceinline__ u16 f2b(float f) {
    union { float f; uint32_t u; } v; v.f = f;
    uint32_t u = v.u;
    return (u16)((u + 0x7fffu + ((u >> 16) & 1u)) >> 16);   // RNE
}

__device__ __forceinline__ void gl_lds16(const u16* g, u16* l) {
    __builtin_amdgcn_global_load_lds(
        (const __attribute__((address_space(1))) unsigned int*)g,
        (__attribute__((address_space(3))) unsigned int*)l, 16, 0, 0);
}
// system-coherent 8B load/store: pure vmcnt (global_*), cross-XCD coherent
__device__ __forceinline__ unsigned long long gld_sys(const u16* p) {
    unsigned long long v;
    asm volatile("global_load_dwordx2 %0, %1, off sc0 sc1"
                 : "=v"(v) : "v"(p) : "memory");
    return v;
}
__device__ __forceinline__ void gst_sys(u16* p, unsigned long long v) {
    asm volatile("global_store_dwordx2 %0, %1, off sc0 sc1"
                 :: "v"(p), "v"(v) : "memory");
}
__device__ __forceinline__ void waitflag(int* f, int n) {
    while (__hip_atomic_load(f, __ATOMIC_RELAXED, __HIP_MEMORY_SCOPE_SYSTEM) < n)
        __builtin_amdgcn_s_sleep(8);
    asm volatile("" ::: "memory");
}
__device__ __forceinline__ void postflag(int* f) {
    __hip_atomic_fetch_add(f, 1, __ATOMIC_RELAXED, __HIP_MEMORY_SCOPE_SYSTEM);
}

// ---------------- prep kernels ----------------

__global__ void k_conv(const float* __restrict__ s, u16* __restrict__ d, int n4) {
    int i = blockIdx.x * blockDim.x + threadIdx.x;
    int st = gridDim.x * blockDim.x;
    for (; i < n4; i += st) {
        float4 v = ((const float4*)s)[i];
        ushort4 o;
        o.x = f2b(v.x); o.y = f2b(v.y); o.z = f2b(v.z); o.w = f2b(v.w);
        ((ushort4*)d)[i] = o;
    }
}

// lin_w [S][H][O] f32 -> [S][O][H] bf16
__global__ __launch_bounds__(256) void k_twl(const float* __restrict__ w, u16* __restrict__ o) {
    __shared__ float tile[32][33];
    int bid = blockIdx.x;
    int t = bid >> 9;
    int rem = bid & 511;
    int j0 = (rem >> 4) << 5;
    int o0 = (rem & 15) << 5;
    int tx = threadIdx.x & 31, ty = threadIdx.x >> 5;
    const float* base = w + (size_t)t * (H_ * O_);
#pragma unroll
    for (int i = 0; i < 4; ++i) {
        int r = ty + (i << 3);
        tile[r][tx] = base[(size_t)(j0 + r) * O_ + o0 + tx];
    }
    __syncthreads();
    u16* ob = o + (size_t)t * (O_ * H_);
#pragma unroll
    for (int i = 0; i < 4; ++i) {
        int r = ty + (i << 3);
        ob[(size_t)(o0 + r) * H_ + j0 + tx] = f2b(tile[tx][r]);
    }
}

// ---------------- persistent dataflow GRU + linear head ----------------
// XCD owns j-slice of every cell's weights; 8 WGs per (cell,XCD) split batch.
// K-loop: 3-buffer Wb, issue-before-wait (2-body lead), + distributed L2
// line-prefetch (1 op/body on wave wid==sub, piece sub of body s+4).

struct GruArgs {
    const u16* Xb;
    const u16 *Wi0, *Wh0, *Wi1, *Wh1, *Wi2, *Wh2;
    const float *bi0, *bh0, *bi1, *bh1, *bi2, *bh2;
    u16 *h0, *h1, *h2a;      // h0,h1: 32-slot rings; h2a: 65 slots (slot t+1 = time t)
    const u16* WLt;          // [S][O][H] bf16
    const float* lb;         // [S][O]
    float* out;              // [B][S][O] then h0,h1,h2 finals
    int* ready;              // [3 cells][64 t]   -> counts to 64
    int* consumed;           // [2 cells][64 t]   -> counts to 128
};

#define VMW(n)  asm volatile("s_waitcnt vmcnt(" #n ")" ::: "memory")
#define LGK0    asm volatile("s_waitcnt lgkmcnt(0)" ::: "memory")
#define SBAR    __builtin_amdgcn_s_barrier()
#define SCHB    __builtin_amdgcn_sched_barrier(0)

__global__ __launch_bounds__(512, 1) void k_gru(GruArgs p) {
    __shared__ u16 Wb[3][3][128 * 64];   // 144 KiB: 3-deep weight buffers (3 gates)
    __shared__ u16 Ab[2][32 * 64];       // 8 KiB A double-buffer
    __shared__ u16 trash[512];           // 1 KiB prefetch sink

    const int w = blockIdx.x;
    const int xcd = w & 7;               // weight j-slice owner (targets XCD via %8)
    const int slot = w >> 3;             // 0..31
    const int role = slot >> 3;          // 0,1,2 = GRU cells; 3 = linear head
    const int sub = slot & 7;            // batch tile
    const int b0 = sub * 32;

    const int tid = threadIdx.x;
    const int wid = tid >> 6, lane = tid & 63;
    const int fr = lane & 15, kc = lane >> 4;

    // A staging constants (A-tile: 32 rows x 64 k, 8B per thread)
    const int arow = tid >> 4;
    const int acol = (tid & 15) << 2;                                        // u16 offset
    const int adst = arow * 64 + ((((tid & 15) >> 1) ^ (arow & 7)) << 3) + ((tid & 1) << 2);

    const int sw0 = ((kc ^ (fr & 7)) << 3);
    const int sw1 = (((4 + kc) ^ (fr & 7)) << 3);

    int* ready = p.ready;
    int* consumed = p.consumed;

    if (role < 3) {
        // ================= GRU cell =================
        const u16 *Wi, *Wh; const float *bi, *bh; int K0;
        if (role == 0)      { Wi = p.Wi0; Wh = p.Wh0; bi = p.bi0; bh = p.bh0; K0 = D_; }
        else if (role == 1) { Wi = p.Wi1; Wh = p.Wh1; bi = p.bi1; bh = p.bh1; K0 = H_; }
        else                { Wi = p.Wi2; Wh = p.Wh2; bi = p.bi2; bh = p.bh2; K0 = H_; }
        const int nXc = K0 >> 6;
        const int nC = nXc + 16;         // 20 or 32 (even)
        const int j0 = xcd * 128;        // weight slice fixed per XCD
        const int jme = j0 + (wid << 4) + fr;
        const float b_r = bi[jme] + bh[jme];
        const float b_z = bi[H_ + jme] + bh[H_ + jme];
        const float b_i = bi[2 * H_ + jme];
        const float b_h = bh[2 * H_ + jme];

        const u16 *A0 = nullptr, *Ah = nullptr; int ld0 = H_;
        u16* hout = nullptr;

        f32x4 hcar[2] = {};              // fp32 recurrent carry in registers

        auto LA = [&](int c) -> unsigned long long {
            const u16* s = (c < nXc) ? (A0 + (size_t)arow * ld0 + (c << 6) + acol)
                                     : (Ah + (size_t)arow * H_ + ((c - nXc) << 6) + acol);
            return gld_sys(s);
        };
        auto SW = [&](int c, int nb) {
            if (c < nXc) {
                int ko = c << 6;
#pragma unroll
                for (int hh = 0; hh < 2; ++hh) {
                    int ci = (hh << 9) + tid, jr = ci >> 3, c8 = ci & 7;
                    size_t ro = (size_t)(j0 + jr) * K0 + ko + ((c8 ^ (jr & 7)) << 3);
                    gl_lds16(Wi + ro,                       &Wb[nb][0][ci << 3]);
                    gl_lds16(Wi + (size_t)H_ * K0 + ro,     &Wb[nb][1][ci << 3]);
                    gl_lds16(Wi + (size_t)2 * H_ * K0 + ro, &Wb[nb][2][ci << 3]);
                }
            } else {
                int ko = (c - nXc) << 6;
#pragma unroll
                for (int hh = 0; hh < 2; ++hh) {
                    int ci = (hh << 9) + tid, jr = ci >> 3, c8 = ci & 7;
                    size_t ro = (size_t)(j0 + jr) * H_ + ko + ((c8 ^ (jr & 7)) << 3);
                    gl_lds16(Wh + ro,                       &Wb[nb][0][ci << 3]);
                    gl_lds16(Wh + (size_t)H_ * H_ + ro,     &Wb[nb][1][ci << 3]);
                    gl_lds16(Wh + (size_t)2 * H_ * H_ + ro, &Wb[nb][2][ci << 3]);
                }
            }
        };

#define CBODY(S_, LAS, LAL, NIMM) do { \
    const int s_ = (S_); \
    LGK0; SBAR; \
    if (s_ + 2 < nC) { LAL = LA(s_ + 2); SW(s_ + 2, (s_ + 2) % 3); } \
    if (wid == sub && s_ + 4 < nC) { \
        int v_ = s_ + 4; int gg_ = lane >> 4; if (gg_ > 2) gg_ = 2; \
        const u16* pb_ = (v_ < nXc) \
            ? Wi + (size_t)(gg_ * H_ + j0 + sub * 16 + (lane & 15)) * K0 + (v_ << 6) \
            : Wh + (size_t)(gg_ * H_ + j0 + sub * 16 + (lane & 15)) * H_ + ((v_ - nXc) << 6); \
        gl_lds16(pb_, trash); \
    } \
    VMW(NIMM); SCHB; \
    if (s_ + 1 < nC) *(unsigned long long*)&Ab[(s_ + 1) & 1][adst] = LAS; \
    const int cur_ = s_ & 1, wcur_ = s_ % 3; \
    const int bo_ = ((wid << 4) + fr) * 64; \
    bf16x8 a00 = *(const bf16x8*)&Ab[cur_][fr * 64 + sw0]; \
    bf16x8 a01 = *(const bf16x8*)&Ab[cur_][fr * 64 + sw1]; \
    bf16x8 a10 = *(const bf16x8*)&Ab[cur_][(16 + fr) * 64 + sw0]; \
    bf16x8 a11 = *(const bf16x8*)&Ab[cur_][(16 + fr) * 64 + sw1]; \
    bf16x8 rr0 = *(const bf16x8*)&Wb[wcur_][0][bo_ + sw0]; \
    bf16x8 rr1 = *(const bf16x8*)&Wb[wcur_][0][bo_ + sw1]; \
    bf16x8 zz0 = *(const bf16x8*)&Wb[wcur_][1][bo_ + sw0]; \
    bf16x8 zz1 = *(const bf16x8*)&Wb[wcur_][1][bo_ + sw1]; \
    bf16x8 qq0 = *(const bf16x8*)&Wb[wcur_][2][bo_ + sw0]; \
    bf16x8 qq1 = *(const bf16x8*)&Wb[wcur_][2][bo_ + sw1]; \
    LGK0; SCHB; \
    __builtin_amdgcn_s_setprio(1); \
    accR[0] = MFMA16(a00, rr0, accR[0]); accR[0] = MFMA16(a01, rr1, accR[0]); \
    accR[1] = MFMA16(a10, rr0, accR[1]); accR[1] = MFMA16(a11, rr1, accR[1]); \
    accZ[0] = MFMA16(a00, zz0, accZ[0]); accZ[0] = MFMA16(a01, zz1, accZ[0]); \
    accZ[1] = MFMA16(a10, zz0, accZ[1]); accZ[1] = MFMA16(a11, zz1, accZ[1]); \
    if (s_ < nXc) { \
        accI[0] = MFMA16(a00, qq0, accI[0]); accI[0] = MFMA16(a01, qq1, accI[0]); \
        accI[1] = MFMA16(a10, qq0, accI[1]); accI[1] = MFMA16(a11, qq1, accI[1]); \
    } else { \
        accN[0] = MFMA16(a00, qq0, accN[0]); accN[0] = MFMA16(a01, qq1, accN[0]); \
        accN[1] = MFMA16(a10, qq0, accN[1]); accN[1] = MFMA16(a11, qq1, accN[1]); \
    } \
    __builtin_amdgcn_s_setprio(0); \
} while (0)

        for (int t = 0; t < S_; ++t) {
            if (role == 0) {
                if (t) waitflag(&ready[0 * 64 + t - 1], 64);
                A0 = p.Xb + (size_t)b0 * (S_ * D_) + t * D_; ld0 = S_ * D_;
                Ah = p.h0 + (size_t)((t + RING_ - 1) & (RING_ - 1)) * BH_ + (size_t)b0 * H_;
                hout = p.h0 + (size_t)(t & (RING_ - 1)) * BH_;
            } else if (role == 1) {
                waitflag(&ready[0 * 64 + t], 64);
                if (t) waitflag(&ready[1 * 64 + t - 1], 64);
                A0 = p.h0 + (size_t)(t & (RING_ - 1)) * BH_ + (size_t)b0 * H_; ld0 = H_;
                Ah = p.h1 + (size_t)((t + RING_ - 1) & (RING_ - 1)) * BH_ + (size_t)b0 * H_;
                hout = p.h1 + (size_t)(t & (RING_ - 1)) * BH_;
            } else {
                waitflag(&ready[1 * 64 + t], 64);
                if (t) waitflag(&ready[2 * 64 + t - 1], 64);
                A0 = p.h1 + (size_t)(t & (RING_ - 1)) * BH_ + (size_t)b0 * H_; ld0 = H_;
                Ah = p.h2a + (size_t)t * BH_ + (size_t)b0 * H_;
                hout = p.h2a + (size_t)(t + 1) * BH_;
            }

            f32x4 accR[2] = {}, accZ[2] = {}, accI[2] = {}, accN[2] = {};

            // prologue: LA(0), SW(0), LA(1), SW(1) -> 14 vm ops; wait all but newest 13
            unsigned long long la0 = LA(0);
            SW(0, 0);
            unsigned long long la1 = LA(1);
            SW(1, 1);
            VMW(13);
            *(unsigned long long*)&Ab[0][adst] = la0;

            for (int s = 0; s + 4 < nC; s += 2) {
                CBODY(s,     la1, la0, 13);
                CBODY(s + 1, la0, la1, 13);
            }
            CBODY(nC - 4, la1, la0, 13);
            CBODY(nC - 3, la0, la1, 13);
            CBODY(nC - 2, la1, la0, 6);
            CBODY(nC - 1, la0, la1, 0);

            // ring backpressure before overwriting slot t & 31
            if (role <= 1 && t >= RING_) waitflag(&consumed[role * 64 + (t - RING_)], 128);

            // gates + state update; fp32 carry in regs, bf16 repack via LDS (Wb[0])
            u16* hrep = &Wb[0][0][0];
#pragma unroll
            for (int m = 0; m < 2; ++m)
#pragma unroll
                for (int i = 0; i < 4; ++i) {
                    int row = m * 16 + kc * 4 + i;
                    float rv = 1.f / (1.f + __expf(-(accR[m][i] + b_r)));
                    float zv = 1.f / (1.f + __expf(-(accZ[m][i] + b_z)));
                    float nv = tanhf(accI[m][i] + b_i + rv * (accN[m][i] + b_h));
                    float hn = (1.f - zv) * nv + zv * hcar[m][i];
                    hcar[m][i] = hn;
                    hrep[row * 128 + (wid << 4) + fr] = f2b(hn);
                }
            __syncthreads();
            {
                int rr = tid >> 4, jo = (tid & 15) << 3;
                unsigned long long v0 = *(const unsigned long long*)&hrep[rr * 128 + jo];
                unsigned long long v1 = *(const unsigned long long*)&hrep[rr * 128 + jo + 4];
                u16* dst = hout + (size_t)(b0 + rr) * H_ + j0 + jo;
                gst_sys(dst, v0);
                gst_sys(dst + 4, v1);
            }
            if (t == S_ - 1) {
                float* ob = p.out + (size_t)B_ * S_ * O_ + (size_t)role * BH_;
#pragma unroll
                for (int m = 0; m < 2; ++m)
#pragma unroll
                    for (int i = 0; i < 4; ++i) {
                        int row = m * 16 + kc * 4 + i;
                        ob[(size_t)(b0 + row) * H_ + jme] = hcar[m][i];
                    }
            }
            asm volatile("s_waitcnt vmcnt(0)" ::: "memory");
            __syncthreads();
            if (tid == 0) {
                postflag(&ready[role * 64 + t]);
                if (role == 0) { if (t) postflag(&consumed[0 * 64 + t - 1]); }
                else if (role == 1) {
                    postflag(&consumed[0 * 64 + t]);
                    if (t) postflag(&consumed[1 * 64 + t - 1]);
                } else {
                    postflag(&consumed[1 * 64 + t]);
                }
            }
            __syncthreads();
            asm volatile("s_waitcnt vmcnt(0) lgkmcnt(0)" ::: "memory");  // ledger reset
        }
#undef CBODY
    } else {
        // ================= linear head (R7-proven, unchanged) =================
        const int o0 = xcd << 6;         // o-slice fixed per XCD
        const int nC = 16;
        const int mg = wid >> 2, og = wid & 3;
        const u16 *A0 = nullptr, *Wl = nullptr;

        auto LAl = [&](int c) -> unsigned long long {
            return gld_sys(A0 + (size_t)arow * H_ + (c << 6) + acol);
        };
        auto SWl = [&](int c, int nb) {
            int orow = tid >> 3, c8 = tid & 7;
            gl_lds16(Wl + (size_t)(o0 + orow) * H_ + (c << 6) + ((c8 ^ (orow & 7)) << 3),
                     &Wb[nb][0][tid << 3]);
        };

        for (int t = 0; t < S_; ++t) {
            waitflag(&ready[2 * 64 + t], 64);
            A0 = p.h2a + (size_t)(t + 1) * BH_ + (size_t)b0 * H_;
            Wl = p.WLt + (size_t)t * (O_ * H_);

            f32x4 acc = {0.f, 0.f, 0.f, 0.f};
            SWl(0, 0);
            unsigned long long la_t = LAl(0);
            unsigned long long r1 = LAl(1);
            unsigned long long r0 = LAl(2);
            SWl(1, 1);
            asm volatile("s_waitcnt vmcnt(3)" ::: "memory");
            *(unsigned long long*)&Ab[0][adst] = la_t;
            asm volatile("s_waitcnt lgkmcnt(0)" ::: "memory");
            SCHB;

            auto BODYL = [&](int s, unsigned long long& laReg) {
                if (s + 2 < nC) asm volatile("s_waitcnt vmcnt(2)" ::: "memory");
                else            asm volatile("s_waitcnt vmcnt(0)" ::: "memory");
                SBAR;
                SCHB;
                if (s + 1 < nC) *(unsigned long long*)&Ab[(s + 1) & 1][adst] = laReg;
                if (s + 3 < nC) laReg = LAl(s + 3);
                if (s + 2 < nC) SWl(s + 2, (s + 2) % 3);
                SCHB;
                const int cur = s & 1;
                const int wcur = s % 3;
                bf16x8 a0 = *(const bf16x8*)&Ab[cur][(mg * 16 + fr) * 64 + sw0];
                bf16x8 a1 = *(const bf16x8*)&Ab[cur][(mg * 16 + fr) * 64 + sw1];
                bf16x8 w0 = *(const bf16x8*)&Wb[wcur][0][(og * 16 + fr) * 64 + sw0];
                bf16x8 w1 = *(const bf16x8*)&Wb[wcur][0][(og * 16 + fr) * 64 + sw1];
                asm volatile("s_waitcnt lgkmcnt(0)" ::: "memory");
                SCHB;
                __builtin_amdgcn_s_setprio(1);
                acc = MFMA16(a0, w0, acc);
                acc = MFMA16(a1, w1, acc);
                __builtin_amdgcn_s_setprio(0);
            };
            for (int s = 0; s < nC; s += 2) { BODYL(s, r1); BODYL(s + 1, r0); }

            float bb = p.lb[t * O_ + o0 + og * 16 + fr];
#pragma unroll
            for (int i = 0; i < 4; ++i) {
                int row = mg * 16 + kc * 4 + i;
                p.out[((size_t)(b0 + row) * S_ + t) * O_ + o0 + og * 16 + fr] = acc[i] + bb;
            }
            asm volatile("s_waitcnt vmcnt(0) lgkmcnt(0)" ::: "memory");
        }
    }
}

// ---------------- launch ----------------

extern "C" void kernel_launch(void* const* d_in, const int* in_sizes, int n_in,
                              void* d_out, int out_size, void* d_ws, size_t ws_size,
                              hipStream_t stream) {
    (void)in_sizes; (void)n_in; (void)out_size; (void)ws_size;
    const float* x   = (const float*)d_in[0];
    const float* wi0 = (const float*)d_in[1];
    const float* wh0 = (const float*)d_in[2];
    const float* bi0 = (const float*)d_in[3];
    const float* bh0 = (const float*)d_in[4];
    const float* wi1 = (const float*)d_in[5];
    const float* wh1 = (const float*)d_in[6];
    const float* bi1 = (const float*)d_in[7];
    const float* bh1 = (const float*)d_in[8];
    const float* wi2 = (const float*)d_in[9];
    const float* wh2 = (const float*)d_in[10];
    const float* bi2 = (const float*)d_in[11];
    const float* bh2 = (const float*)d_in[12];
    const float* lw  = (const float*)d_in[13];
    const float* lb  = (const float*)d_in[14];

    char* base = (char*)d_ws;
    size_t off = 0;
    auto alloc = [&](size_t bytes) {
        char* p = base + off;
        off = (off + bytes + 255) & ~(size_t)255;
        return p;
    };
    u16* Xb  = (u16*)alloc((size_t)B_ * S_ * D_ * 2);
    u16* Wi0 = (u16*)alloc((size_t)G_ * D_ * 2);
    u16* Wh0 = (u16*)alloc((size_t)G_ * H_ * 2);
    u16* Wi1 = (u16*)alloc((size_t)G_ * H_ * 2);
    u16* Wh1 = (u16*)alloc((size_t)G_ * H_ * 2);
    u16* Wi2 = (u16*)alloc((size_t)G_ * H_ * 2);
    u16* Wh2 = (u16*)alloc((size_t)G_ * H_ * 2);
    u16* h0  = (u16*)alloc((size_t)RING_ * BH_ * 2);
    u16* h1  = (u16*)alloc((size_t)RING_ * BH_ * 2);
    u16* h2a = (u16*)alloc((size_t)(S_ + 1) * BH_ * 2);
    u16* WLt = (u16*)alloc((size_t)S_ * O_ * H_ * 2);
    int* flags = (int*)alloc((size_t)(3 * 64 + 2 * 64) * 4);
    int* ready = flags;
    int* consumed = flags + 3 * 64;

    k_conv<<<1024, 256, 0, stream>>>(x,   Xb,  (B_ * S_ * D_) / 4);
    k_conv<<<1024, 256, 0, stream>>>(wi0, Wi0, (G_ * D_) / 4);
    k_conv<<<1024, 256, 0, stream>>>(wh0, Wh0, (G_ * H_) / 4);
    k_conv<<<1024, 256, 0, stream>>>(wi1, Wi1, (G_ * H_) / 4);
    k_conv<<<1024, 256, 0, stream>>>(wh1, Wh1, (G_ * H_) / 4);
    k_conv<<<1024, 256, 0, stream>>>(wi2, Wi2, (G_ * H_) / 4);
    k_conv<<<1024, 256, 0, stream>>>(wh2, Wh2, (G_ * H_) / 4);
    k_twl<<<S_ * 512, 256, 0, stream>>>(lw, WLt);
    hipMemsetAsync(h0 + (size_t)(RING_ - 1) * BH_, 0, (size_t)BH_ * 2, stream);  // h0[-1]=0
    hipMemsetAsync(h1 + (size_t)(RING_ - 1) * BH_, 0, (size_t)BH_ * 2, stream);  // h1[-1]=0
    hipMemsetAsync(h2a, 0, (size_t)BH_ * 2, stream);                             // h2[-1]=0
    hipMemsetAsync(flags, 0, (size_t)(3 * 64 + 2 * 64) * 4, stream);

    GruArgs ga;
    ga.Xb = Xb;
    ga.Wi0 = Wi0; ga.Wh0 = Wh0; ga.Wi1 = Wi1; ga.Wh1 = Wh1; ga.Wi2 = Wi2; ga.Wh2 = Wh2;
    ga.bi0 = bi0; ga.bh0 = bh0; ga.bi1 = bi1; ga.bh1 = bh1; ga.bi2 = bi2; ga.bh2 = bh2;
    ga.h0 = h0; ga.h1 = h1; ga.h2a = h2a;
    ga.WLt = WLt; ga.lb = lb; ga.out = (float*)d_out;
    ga.ready = ready; ga.consumed = consumed;

    void* args[] = {&ga};
    hipLaunchCooperativeKernel((void*)k_gru, dim3(256), dim3(512), args, 0, stream);
}